// Round 4
// baseline (694.209 us; speedup 1.0000x reference)
//
#include <hip/hip_runtime.h>
#include <cstdint>
#include <cstddef>

#define B_  2
#define S_  2048
#define D_  2560
#define H_  32
#define HD_ 80

typedef __attribute__((ext_vector_type(8))) short  short8;
typedef __attribute__((ext_vector_type(4))) float  floatx4;

__device__ __forceinline__ float b2f(unsigned short u) {
  union { unsigned int i; float f; } x; x.i = ((unsigned int)u) << 16; return x.f;
}
__device__ __forceinline__ unsigned short f2bf(float f) {
  union { float f; unsigned int i; } x; x.f = f;
  unsigned int u = x.i;
  return (unsigned short)((u + 0x7fffu + ((u >> 16) & 1u)) >> 16);
}

// fused fp32 -> bf16 for all three inputs (one launch)
__global__ void cvt3_kernel(const float* __restrict__ s0, unsigned short* __restrict__ d0, int n0,
                            const float* __restrict__ s1, unsigned short* __restrict__ d1, int n1,
                            const float* __restrict__ s2, unsigned short* __restrict__ d2, int n2) {
  int j = blockIdx.x * 256 + threadIdx.x;
  const float* s; unsigned short* d;
  if (j < n0) { s = s0; d = d0; }
  else {
    j -= n0;
    if (j < n1) { s = s1; d = d1; }
    else { j -= n1; if (j >= n2) return; s = s2; d = d2; }
  }
  const float4 v = ((const float4*)s)[j];
  ushort4 r;
  r.x = f2bf(v.x); r.y = f2bf(v.y); r.z = f2bf(v.z); r.w = f2bf(v.w);
  ((ushort4*)d)[j] = r;
}

#define GLOAD_LDS16(g, l)                                                      \
  __builtin_amdgcn_global_load_lds(                                            \
      (const __attribute__((address_space(1))) void*)(g),                      \
      (__attribute__((address_space(3))) void*)(l), 16, 0, 0)

// C[M,N] = A[M,K] * B[N,K]^T + bias[N]; A,B bf16 row-major; C bf16 or fp32.
// MFMA computes C^T (operands swapped) so each lane owns 4 consecutive n -> packed stores.
template <int OUT_BF16>
__global__ __launch_bounds__(256)
void gemm_bt(const unsigned short* __restrict__ A,
             const unsigned short* __restrict__ B,
             const float* __restrict__ bias,
             void* __restrict__ Cv,
             const int M, const int N, const int K) {
  __shared__ unsigned short As[128 * 32];
  __shared__ unsigned short Bs[128 * 32];
  const int tid  = threadIdx.x;
  const int wave = tid >> 6;
  const int lane = tid & 63;
  const int wm   = (wave & 1) << 6;
  const int wn   = (wave >> 1) << 6;
  const int row0 = (int)blockIdx.y << 7;
  const int col0 = (int)blockIdx.x << 7;
  const unsigned short* Ab = A + (size_t)row0 * K;
  const unsigned short* Bb = B + (size_t)col0 * K;
  const int srow = wave * 16 + (lane >> 2);
  const int scol = (lane & 3) << 3;
  const int fr = lane & 15;
  const int fq = (lane >> 4) << 3;
  floatx4 acc[4][4] = {};  // acc[mi][ni] holds C^T tile: row=n, col=m

  for (int k0 = 0; k0 < K; k0 += 32) {
    __syncthreads();
    GLOAD_LDS16(Ab + (size_t)srow        * K + (k0 + scol), &As[wave * 512]);
    GLOAD_LDS16(Ab + (size_t)(srow + 64) * K + (k0 + scol), &As[2048 + wave * 512]);
    GLOAD_LDS16(Bb + (size_t)srow        * K + (k0 + scol), &Bs[wave * 512]);
    GLOAD_LDS16(Bb + (size_t)(srow + 64) * K + (k0 + scol), &Bs[2048 + wave * 512]);
    __syncthreads();
    short8 aF[4], bF[4];
#pragma unroll
    for (int i = 0; i < 4; i++) aF[i] = *(const short8*)(&As[(wm + i * 16 + fr) * 32 + fq]);
#pragma unroll
    for (int i = 0; i < 4; i++) bF[i] = *(const short8*)(&Bs[(wn + i * 16 + fr) * 32 + fq]);
#pragma unroll
    for (int mi = 0; mi < 4; mi++)
#pragma unroll
      for (int ni = 0; ni < 4; ni++)
        acc[mi][ni] = __builtin_amdgcn_mfma_f32_16x16x32_bf16(bF[ni], aF[mi], acc[mi][ni], 0, 0, 0);
  }

  // C^T layout: lane holds C[m = mi*16+fr][n = ni*16 + fg*4 + r], r=0..3 consecutive n
  const int fg = lane >> 4;
  unsigned short* Cb = (unsigned short*)Cv;
  float* Cf = (float*)Cv;
#pragma unroll
  for (int mi = 0; mi < 4; mi++) {
    const size_t rowoff = (size_t)(row0 + wm + mi * 16 + fr) * N;
#pragma unroll
    for (int ni = 0; ni < 4; ni++) {
      const int nbase = col0 + wn + ni * 16 + fg * 4;
      const float4 bv = *(const float4*)&bias[nbase];
      float v0 = acc[mi][ni][0] + bv.x;
      float v1 = acc[mi][ni][1] + bv.y;
      float v2 = acc[mi][ni][2] + bv.z;
      float v3 = acc[mi][ni][3] + bv.w;
      if (OUT_BF16) {
        uint2 w;
        w.x = (unsigned)f2bf(v0) | ((unsigned)f2bf(v1) << 16);
        w.y = (unsigned)f2bf(v2) | ((unsigned)f2bf(v3) << 16);
        *(uint2*)&Cb[rowoff + nbase] = w;
      } else {
        float4 w; w.x = v0; w.y = v1; w.z = v2; w.w = v3;
        *(float4*)&Cf[rowoff + nbase] = w;
      }
    }
  }
}

// qkv[B,S,3,H,HD] bf16 -> Q,K [B,H,S,HD] bf16; rope; Q scaled by (1/sqrt(80))*log2(e).
__global__ void rope_kernel(const unsigned short* __restrict__ qkv,
                            unsigned short* __restrict__ Q,
                            unsigned short* __restrict__ K) {
  const int idx = blockIdx.x * 256 + threadIdx.x;
  if (idx >= B_ * S_ * H_) return;
  const int h = idx & (H_ - 1);
  const int s = (idx >> 5) & (S_ - 1);
  const int b = idx >> 16;
  const unsigned short* row = qkv + (size_t)(b * S_ + s) * (3 * D_);
  const size_t obase = ((size_t)(b * H_ + h) * S_ + s) * HD_;

  float cc[16], ssn[16];
#pragma unroll
  for (int i = 0; i < 16; i++) {
    const float ang = (float)s * exp2f((float)i * -0.83048202372184059f);
    ssn[i] = sinf(ang);
    cc[i]  = cosf(ang);
  }
  {
    const float QS = 0.11180339887498949f * 1.4426950408889634f;
    const uint4* src = (const uint4*)(row + h * HD_);
    float f[80], g[80];
#pragma unroll
    for (int i = 0; i < 10; i++) {
      uint4 t = src[i];
      const unsigned short* w = (const unsigned short*)&t;
#pragma unroll
      for (int j = 0; j < 8; j++) f[i * 8 + j] = b2f(w[j]);
    }
#pragma unroll
    for (int i = 0; i < 16; i++) {
      g[i]      = f[i] * cc[i] - f[i + 16] * ssn[i];
      g[i + 16] = f[i] * ssn[i] + f[i + 16] * cc[i];
    }
#pragma unroll
    for (int i = 32; i < 80; i++) g[i] = f[i];
    uint4* dst = (uint4*)(Q + obase);
#pragma unroll
    for (int i = 0; i < 10; i++) {
      uint4 t;
      unsigned short* w = (unsigned short*)&t;
#pragma unroll
      for (int j = 0; j < 8; j++) w[j] = f2bf(g[i * 8 + j] * QS);
      dst[i] = t;
    }
  }
  {
    const uint4* src = (const uint4*)(row + (H_ + h) * HD_);
    float f[32], g[32];
#pragma unroll
    for (int i = 0; i < 4; i++) {
      uint4 t = src[i];
      const unsigned short* w = (const unsigned short*)&t;
#pragma unroll
      for (int j = 0; j < 8; j++) f[i * 8 + j] = b2f(w[j]);
    }
#pragma unroll
    for (int i = 0; i < 16; i++) {
      g[i]      = f[i] * cc[i] - f[i + 16] * ssn[i];
      g[i + 16] = f[i] * ssn[i] + f[i + 16] * cc[i];
    }
    uint4* dst = (uint4*)(K + obase);
#pragma unroll
    for (int i = 0; i < 4; i++) {
      uint4 t;
      unsigned short* w = (unsigned short*)&t;
#pragma unroll
      for (int j = 0; j < 8; j++) w[j] = f2bf(g[i * 8 + j]);
      dst[i] = t;
    }
#pragma unroll
    for (int i = 4; i < 10; i++) dst[i] = src[i];
  }
}

// V slice of qkv -> tiles Vtile[bh][s-chunk64][80][64], cols XOR-swizzled by (d&7)*8.
__global__ __launch_bounds__(256)
void vtrans_kernel(const unsigned short* __restrict__ qkv, unsigned short* __restrict__ Vt) {
  __shared__ unsigned short T[64][88];
  const int tid = threadIdx.x;
  const int bh = blockIdx.y;
  const int b = bh >> 5, h = bh & 31;
  const int tile = blockIdx.x;
  const int s0 = tile * 64;
  for (int t = tid; t < 640; t += 256) {
    const int r = t / 10, c = t % 10;
    const size_t src = ((size_t)((b * S_ + s0 + r) * 3) + 2) * D_ + h * HD_ + c * 8;
    *(uint4*)&T[r][c * 8] = *(const uint4*)&qkv[src];
  }
  __syncthreads();
  unsigned short* tb = Vt + ((size_t)bh * 32 + tile) * 5120;
  for (int t = tid; t < 640; t += 256) {
    const int d = t / 8, sc = t % 8;
    uint4 o;
    unsigned short* w = (unsigned short*)&o;
#pragma unroll
    for (int j = 0; j < 8; j++) w[j] = T[sc * 8 + j][d];
    *(uint4*)&tb[d * 64 + ((sc * 8) ^ ((d & 7) * 8))] = o;
  }
}

// MFMA flash attention, S^T form: P lands with k contiguous per lane.
// block = 4 waves, 128 queries per (b,h); K-chunks of 64; fixed-max exp2 softmax.
__global__ __launch_bounds__(256, 4)
void attn_mfma(const unsigned short* __restrict__ Qg,
               const unsigned short* __restrict__ Kg,
               const unsigned short* __restrict__ Vtg,
               unsigned short* __restrict__ ctx) {
  __shared__ unsigned short Ks[64 * 80];    // [k][80] (DMA-contiguous)
  __shared__ unsigned short Vs[80 * 64];    // [d][64], XOR-swizzled cols (DMA-contiguous)
  __shared__ unsigned short Ts[4][32 * 40]; // per-wave P^T staging, half-chunk (32 k), pad 40

  const int tid  = threadIdx.x;
  const int wave = tid >> 6;
  const int lane = tid & 63;
  const int fr   = lane & 15;
  const int fg   = lane >> 4;
  const int bh   = blockIdx.y;
  const int qt   = (int)gridDim.x - 1 - (int)blockIdx.x;  // heavy tiles first
  const int qbase = (qt << 7) + wave * 32;

  const unsigned short* Qrow  = Qg  + (size_t)bh * S_ * HD_;
  const unsigned short* Krow  = Kg  + (size_t)bh * S_ * HD_;
  const unsigned short* Vtile = Vtg + (size_t)bh * 32 * 5120;

  // Q fragments (B-operand): rows q, contiguous d; 3rd step zeroed for fg>=2
  short8 qf[2][3];
  const short8 zfrag = {};
#pragma unroll
  for (int mi = 0; mi < 2; mi++) {
    const unsigned short* qp = Qrow + (size_t)(qbase + mi * 16 + fr) * HD_;
    qf[mi][0] = *(const short8*)&qp[fg * 8];
    qf[mi][1] = *(const short8*)&qp[32 + fg * 8];
    qf[mi][2] = (fg < 2) ? *(const short8*)&qp[64 + fg * 8] : zfrag;
  }

  floatx4 accOT[5][2] = {};   // O^T: lane holds O[q=mi*16+fr][d=dt*16+fg*4+r]
  float l_part[2] = {0.f, 0.f};

  const int nch = 2 * qt + 2;
  for (int c = 0; c < nch; c++) {
    const int k0 = c * 64;
    __syncthreads();  // prior chunk's Ks/Vs reads complete
    {
      const unsigned short* Kt = Krow + (size_t)k0 * HD_;
      for (int i = wave; i < 10; i += 4)
        GLOAD_LDS16(Kt + i * 512 + lane * 8, &Ks[i * 512]);
    }
    {
      const unsigned short* Vt = Vtile + (size_t)c * 5120;
      for (int i = wave; i < 10; i += 4)
        GLOAD_LDS16(Vt + i * 512 + lane * 8, &Vs[i * 512]);
    }
    __syncthreads();  // drains DMA

    // S^T = K Q^T: accST[ni][mi] lane holds P[q=mi*16+fr][k=ni*16+fg*4+r]
    floatx4 accST[4][2] = {};
#pragma unroll
    for (int ni = 0; ni < 4; ni++) {
      const unsigned short* kp = &Ks[(ni * 16 + fr) * 80];
      const short8 kf0 = *(const short8*)&kp[fg * 8];
      const short8 kf1 = *(const short8*)&kp[32 + fg * 8];
      const short8 kf2 = *(const short8*)&kp[64 + (fg & 1) * 8];  // fg>=2: qf side is zero
      accST[ni][0] = __builtin_amdgcn_mfma_f32_16x16x32_bf16(kf0, qf[0][0], accST[ni][0], 0, 0, 0);
      accST[ni][1] = __builtin_amdgcn_mfma_f32_16x16x32_bf16(kf0, qf[1][0], accST[ni][1], 0, 0, 0);
      accST[ni][0] = __builtin_amdgcn_mfma_f32_16x16x32_bf16(kf1, qf[0][1], accST[ni][0], 0, 0, 0);
      accST[ni][1] = __builtin_amdgcn_mfma_f32_16x16x32_bf16(kf1, qf[1][1], accST[ni][1], 0, 0, 0);
      accST[ni][0] = __builtin_amdgcn_mfma_f32_16x16x32_bf16(kf2, qf[0][2], accST[ni][0], 0, 0, 0);
      accST[ni][1] = __builtin_amdgcn_mfma_f32_16x16x32_bf16(kf2, qf[1][2], accST[ni][1], 0, 0, 0);
    }

    // causal mask (diagonal-crossing chunks only)
    if (k0 + 63 > qbase) {
#pragma unroll
      for (int ni = 0; ni < 4; ni++)
#pragma unroll
        for (int mi = 0; mi < 2; mi++) {
          const int qg = qbase + mi * 16 + fr;
#pragma unroll
          for (int r = 0; r < 4; r++) {
            const int kg = k0 + ni * 16 + fg * 4 + r;
            if (kg > qg) accST[ni][mi][r] = -1e30f;
          }
        }
    }

    // per 32-key half: exp2 -> packed P^T to LDS -> PV MFMA
#pragma unroll
    for (int hh = 0; hh < 2; hh++) {
#pragma unroll
      for (int nh = 0; nh < 2; nh++) {
        const int ni = hh * 2 + nh;
#pragma unroll
        for (int mi = 0; mi < 2; mi++) {
          const float p0 = __builtin_amdgcn_exp2f(accST[ni][mi][0]);
          const float p1 = __builtin_amdgcn_exp2f(accST[ni][mi][1]);
          const float p2 = __builtin_amdgcn_exp2f(accST[ni][mi][2]);
          const float p3 = __builtin_amdgcn_exp2f(accST[ni][mi][3]);
          l_part[mi] += (p0 + p1) + (p2 + p3);
          uint2 w;
          w.x = (unsigned)f2bf(p0) | ((unsigned)f2bf(p1) << 16);
          w.y = (unsigned)f2bf(p2) | ((unsigned)f2bf(p3) << 16);
          *(uint2*)&Ts[wave][(mi * 16 + fr) * 40 + nh * 16 + fg * 4] = w;
        }
      }
      // wave-local write->read; compiler inserts lgkmcnt
      const short8 pf0 = *(const short8*)&Ts[wave][fr * 40 + fg * 8];
      const short8 pf1 = *(const short8*)&Ts[wave][(16 + fr) * 40 + fg * 8];
      const int vcol = hh * 32 + fg * 8;
#pragma unroll
      for (int dt = 0; dt < 5; dt++) {
        const short8 vf = *(const short8*)&Vs[(dt * 16 + fr) * 64 + (vcol ^ ((fr & 7) * 8))];
        accOT[dt][0] = __builtin_amdgcn_mfma_f32_16x16x32_bf16(vf, pf0, accOT[dt][0], 0, 0, 0);
        accOT[dt][1] = __builtin_amdgcn_mfma_f32_16x16x32_bf16(vf, pf1, accOT[dt][1], 0, 0, 0);
      }
    }
  }

  // epilogue: l reduce across fg lanes; packed b64 ctx stores (4 consecutive d)
  const int b = bh >> 5, h2 = bh & 31;
#pragma unroll
  for (int mi = 0; mi < 2; mi++) {
    float s = l_part[mi];
    s += __shfl_xor(s, 16);
    s += __shfl_xor(s, 32);
    const float inv = 1.f / s;
    const size_t rowoff = (size_t)(b * S_ + qbase + mi * 16 + fr) * D_ + h2 * HD_;
#pragma unroll
    for (int dt = 0; dt < 5; dt++) {
      const float v0 = accOT[dt][mi][0] * inv;
      const float v1 = accOT[dt][mi][1] * inv;
      const float v2 = accOT[dt][mi][2] * inv;
      const float v3 = accOT[dt][mi][3] * inv;
      uint2 w;
      w.x = (unsigned)f2bf(v0) | ((unsigned)f2bf(v1) << 16);
      w.y = (unsigned)f2bf(v2) | ((unsigned)f2bf(v3) << 16);
      *(uint2*)&ctx[rowoff + dt * 16 + fg * 4] = w;
    }
  }
}

extern "C" void kernel_launch(void* const* d_in, const int* in_sizes, int n_in,
                              void* d_out, int out_size, void* d_ws, size_t ws_size,
                              hipStream_t stream) {
  (void)in_sizes; (void)n_in; (void)out_size; (void)ws_size;
  const float* x      = (const float*)d_in[0];
  const float* wqkv_w = (const float*)d_in[1];
  const float* wqkv_b = (const float*)d_in[2];
  const float* out_w  = (const float*)d_in[3];
  const float* out_b  = (const float*)d_in[4];
  char* ws = (char*)d_ws;

  unsigned short* Xb    = (unsigned short*)(ws + 0);          // 4096x2560 bf16
  unsigned short* Wqkvb = (unsigned short*)(ws + 20971520);   // 7680x2560 bf16 (dead after gemm1)
  unsigned short* qkv   = (unsigned short*)(ws + 60293120);   // 4096x7680 bf16
  unsigned short* Qb    = (unsigned short*)(ws + 123207680);  // [B,H,S,80] bf16
  unsigned short* Kb    = (unsigned short*)(ws + 144179200);  // [B,H,S,80] bf16
  unsigned short* Woutb = (unsigned short*)(ws + 165150720);  // 2560x2560 bf16; end 178.3 MB
  unsigned short* ctx   = Xb;                                 // Xb dead after gemm1
  unsigned short* Vtile = (unsigned short*)(ws + 34078720);   // 21.0 MB in dead Wqkvb tail

  cvt3_kernel<<<35840, 256, 0, stream>>>(x, Xb, 2621440,
                                         wqkv_w, Wqkvb, 4915200,
                                         out_w, Woutb, 1638400);
  gemm_bt<1><<<dim3(60, 32), 256, 0, stream>>>(Xb, Wqkvb, wqkv_b, (void*)qkv, 4096, 7680, 2560);
  rope_kernel<<<512, 256, 0, stream>>>(qkv, Qb, Kb);
  vtrans_kernel<<<dim3(32, 64), 256, 0, stream>>>(qkv, Vtile);
  attn_mfma<<<dim3(16, 64), 256, 0, stream>>>(Qb, Kb, Vtile, ctx);
  gemm_bt<0><<<dim3(20, 32), 256, 0, stream>>>(ctx, Woutb, out_b, d_out, 4096, 2560, 2560);
}

// Round 5
// 649.189 us; speedup vs baseline: 1.0693x; 1.0693x over previous
//
#include <hip/hip_runtime.h>
#include <cstdint>
#include <cstddef>

#define B_  2
#define S_  2048
#define D_  2560
#define H_  32
#define HD_ 80

typedef __attribute__((ext_vector_type(8))) short  short8;
typedef __attribute__((ext_vector_type(4))) float  floatx4;

__device__ __forceinline__ float b2f(unsigned short u) {
  union { unsigned int i; float f; } x; x.i = ((unsigned int)u) << 16; return x.f;
}
__device__ __forceinline__ unsigned short f2bf(float f) {
  union { float f; unsigned int i; } x; x.f = f;
  unsigned int u = x.i;
  return (unsigned short)((u + 0x7fffu + ((u >> 16) & 1u)) >> 16);
}

// fused fp32 -> bf16 for all three inputs (one launch)
__global__ void cvt3_kernel(const float* __restrict__ s0, unsigned short* __restrict__ d0, int n0,
                            const float* __restrict__ s1, unsigned short* __restrict__ d1, int n1,
                            const float* __restrict__ s2, unsigned short* __restrict__ d2, int n2) {
  int j = blockIdx.x * 256 + threadIdx.x;
  const float* s; unsigned short* d;
  if (j < n0) { s = s0; d = d0; }
  else {
    j -= n0;
    if (j < n1) { s = s1; d = d1; }
    else { j -= n1; if (j >= n2) return; s = s2; d = d2; }
  }
  const float4 v = ((const float4*)s)[j];
  ushort4 r;
  r.x = f2bf(v.x); r.y = f2bf(v.y); r.z = f2bf(v.z); r.w = f2bf(v.w);
  ((ushort4*)d)[j] = r;
}

#define GLOAD_LDS16(g, l)                                                      \
  __builtin_amdgcn_global_load_lds(                                            \
      (const __attribute__((address_space(1))) void*)(g),                      \
      (__attribute__((address_space(3))) void*)(l), 16, 0, 0)

// C[M,N] = A[M,K] * B[N,K]^T + bias[N]; A,B bf16 row-major; C bf16 or fp32.
// R2 configuration (MfmaUtil 30%): original operand order; epilogue stores
// coalesce into 4x64B row segments per instr. Do NOT swap operands for packed
// stores — R3 showed that scatters stores across 16 rows (+47 us, +21 MB fetch).
template <int OUT_BF16>
__global__ __launch_bounds__(256)
void gemm_bt(const unsigned short* __restrict__ A,
             const unsigned short* __restrict__ B,
             const float* __restrict__ bias,
             void* __restrict__ Cv,
             const int M, const int N, const int K) {
  __shared__ unsigned short As[128 * 32];
  __shared__ unsigned short Bs[128 * 32];
  const int tid  = threadIdx.x;
  const int wave = tid >> 6;
  const int lane = tid & 63;
  const int wm   = (wave & 1) << 6;
  const int wn   = (wave >> 1) << 6;
  const int row0 = (int)blockIdx.y << 7;
  const int col0 = (int)blockIdx.x << 7;
  const unsigned short* Ab = A + (size_t)row0 * K;
  const unsigned short* Bb = B + (size_t)col0 * K;
  const int srow = wave * 16 + (lane >> 2);
  const int scol = (lane & 3) << 3;
  const int fr = lane & 15;
  const int fq = (lane >> 4) << 3;
  floatx4 acc[4][4] = {};

  for (int k0 = 0; k0 < K; k0 += 32) {
    __syncthreads();
    GLOAD_LDS16(Ab + (size_t)srow        * K + (k0 + scol), &As[wave * 512]);
    GLOAD_LDS16(Ab + (size_t)(srow + 64) * K + (k0 + scol), &As[2048 + wave * 512]);
    GLOAD_LDS16(Bb + (size_t)srow        * K + (k0 + scol), &Bs[wave * 512]);
    GLOAD_LDS16(Bb + (size_t)(srow + 64) * K + (k0 + scol), &Bs[2048 + wave * 512]);
    __syncthreads();
    short8 aF[4], bF[4];
#pragma unroll
    for (int i = 0; i < 4; i++) aF[i] = *(const short8*)(&As[(wm + i * 16 + fr) * 32 + fq]);
#pragma unroll
    for (int i = 0; i < 4; i++) bF[i] = *(const short8*)(&Bs[(wn + i * 16 + fr) * 32 + fq]);
#pragma unroll
    for (int mi = 0; mi < 4; mi++)
#pragma unroll
      for (int ni = 0; ni < 4; ni++)
        acc[mi][ni] = __builtin_amdgcn_mfma_f32_16x16x32_bf16(aF[mi], bF[ni], acc[mi][ni], 0, 0, 0);
  }

  const int cr = (lane >> 4) << 2;
  const int cn = lane & 15;
  unsigned short* Cb = (unsigned short*)Cv;
  float* Cf = (float*)Cv;
#pragma unroll
  for (int ni = 0; ni < 4; ni++) {
    const int col = col0 + wn + ni * 16 + cn;
    const float bv = bias[col];
#pragma unroll
    for (int mi = 0; mi < 4; mi++) {
      const int rowb = row0 + wm + mi * 16 + cr;
#pragma unroll
      for (int r = 0; r < 4; r++) {
        const float v = acc[mi][ni][r] + bv;
        const size_t idx = (size_t)(rowb + r) * N + col;
        if (OUT_BF16) Cb[idx] = f2bf(v);
        else          Cf[idx] = v;
      }
    }
  }
}

// qkv[B,S,3,H,HD] bf16 -> Q,K [B,H,S,HD] bf16; rope; Q scaled by (1/sqrt(80))*log2(e).
__global__ void rope_kernel(const unsigned short* __restrict__ qkv,
                            unsigned short* __restrict__ Q,
                            unsigned short* __restrict__ K) {
  const int idx = blockIdx.x * 256 + threadIdx.x;
  if (idx >= B_ * S_ * H_) return;
  const int h = idx & (H_ - 1);
  const int s = (idx >> 5) & (S_ - 1);
  const int b = idx >> 16;
  const unsigned short* row = qkv + (size_t)(b * S_ + s) * (3 * D_);
  const size_t obase = ((size_t)(b * H_ + h) * S_ + s) * HD_;

  float cc[16], ssn[16];
#pragma unroll
  for (int i = 0; i < 16; i++) {
    const float ang = (float)s * exp2f((float)i * -0.83048202372184059f);
    ssn[i] = sinf(ang);
    cc[i]  = cosf(ang);
  }
  {
    const float QS = 0.11180339887498949f * 1.4426950408889634f;
    const uint4* src = (const uint4*)(row + h * HD_);
    float f[80], g[80];
#pragma unroll
    for (int i = 0; i < 10; i++) {
      uint4 t = src[i];
      const unsigned short* w = (const unsigned short*)&t;
#pragma unroll
      for (int j = 0; j < 8; j++) f[i * 8 + j] = b2f(w[j]);
    }
#pragma unroll
    for (int i = 0; i < 16; i++) {
      g[i]      = f[i] * cc[i] - f[i + 16] * ssn[i];
      g[i + 16] = f[i] * ssn[i] + f[i + 16] * cc[i];
    }
#pragma unroll
    for (int i = 32; i < 80; i++) g[i] = f[i];
    uint4* dst = (uint4*)(Q + obase);
#pragma unroll
    for (int i = 0; i < 10; i++) {
      uint4 t;
      unsigned short* w = (unsigned short*)&t;
#pragma unroll
      for (int j = 0; j < 8; j++) w[j] = f2bf(g[i * 8 + j] * QS);
      dst[i] = t;
    }
  }
  {
    const uint4* src = (const uint4*)(row + (H_ + h) * HD_);
    float f[32], g[32];
#pragma unroll
    for (int i = 0; i < 4; i++) {
      uint4 t = src[i];
      const unsigned short* w = (const unsigned short*)&t;
#pragma unroll
      for (int j = 0; j < 8; j++) f[i * 8 + j] = b2f(w[j]);
    }
#pragma unroll
    for (int i = 0; i < 16; i++) {
      g[i]      = f[i] * cc[i] - f[i + 16] * ssn[i];
      g[i + 16] = f[i] * ssn[i] + f[i + 16] * cc[i];
    }
    uint4* dst = (uint4*)(K + obase);
#pragma unroll
    for (int i = 0; i < 4; i++) {
      uint4 t;
      unsigned short* w = (unsigned short*)&t;
#pragma unroll
      for (int j = 0; j < 8; j++) w[j] = f2bf(g[i * 8 + j]);
      dst[i] = t;
    }
#pragma unroll
    for (int i = 4; i < 10; i++) dst[i] = src[i];
  }
}

// V slice of qkv -> tiles Vtile[bh][s-chunk64][80][64], cols XOR-swizzled by (d&7)*8.
__global__ __launch_bounds__(256)
void vtrans_kernel(const unsigned short* __restrict__ qkv, unsigned short* __restrict__ Vt) {
  __shared__ unsigned short T[64][88];
  const int tid = threadIdx.x;
  const int bh = blockIdx.y;
  const int b = bh >> 5, h = bh & 31;
  const int tile = blockIdx.x;
  const int s0 = tile * 64;
  for (int t = tid; t < 640; t += 256) {
    const int r = t / 10, c = t % 10;
    const size_t src = ((size_t)((b * S_ + s0 + r) * 3) + 2) * D_ + h * HD_ + c * 8;
    *(uint4*)&T[r][c * 8] = *(const uint4*)&qkv[src];
  }
  __syncthreads();
  unsigned short* tb = Vt + ((size_t)bh * 32 + tile) * 5120;
  for (int t = tid; t < 640; t += 256) {
    const int d = t / 8, sc = t % 8;
    uint4 o;
    unsigned short* w = (unsigned short*)&o;
#pragma unroll
    for (int j = 0; j < 8; j++) w[j] = T[sc * 8 + j][d];
    *(uint4*)&tb[d * 64 + ((sc * 8) ^ ((d & 7) * 8))] = o;
  }
}

// MFMA flash attention, S^T form: P lands with k contiguous per lane.
// block = 4 waves, 128 queries per (b,h); K-chunks of 64; fixed-max exp2 softmax.
__global__ __launch_bounds__(256, 4)
void attn_mfma(const unsigned short* __restrict__ Qg,
               const unsigned short* __restrict__ Kg,
               const unsigned short* __restrict__ Vtg,
               unsigned short* __restrict__ ctx) {
  __shared__ unsigned short Ks[64 * 80];    // [k][80] (DMA-contiguous)
  __shared__ unsigned short Vs[80 * 64];    // [d][64], XOR-swizzled cols (DMA-contiguous)
  __shared__ unsigned short Ts[4][32 * 40]; // per-wave P^T staging, half-chunk (32 k), pad 40

  const int tid  = threadIdx.x;
  const int wave = tid >> 6;
  const int lane = tid & 63;
  const int fr   = lane & 15;
  const int fg   = lane >> 4;
  const int bh   = blockIdx.y;
  const int qt   = (int)gridDim.x - 1 - (int)blockIdx.x;  // heavy tiles first
  const int qbase = (qt << 7) + wave * 32;

  const unsigned short* Qrow  = Qg  + (size_t)bh * S_ * HD_;
  const unsigned short* Krow  = Kg  + (size_t)bh * S_ * HD_;
  const unsigned short* Vtile = Vtg + (size_t)bh * 32 * 5120;

  // Q fragments (B-operand): rows q, contiguous d; 3rd step zeroed for fg>=2
  short8 qf[2][3];
  const short8 zfrag = {};
#pragma unroll
  for (int mi = 0; mi < 2; mi++) {
    const unsigned short* qp = Qrow + (size_t)(qbase + mi * 16 + fr) * HD_;
    qf[mi][0] = *(const short8*)&qp[fg * 8];
    qf[mi][1] = *(const short8*)&qp[32 + fg * 8];
    qf[mi][2] = (fg < 2) ? *(const short8*)&qp[64 + fg * 8] : zfrag;
  }

  floatx4 accOT[5][2] = {};   // O^T: lane holds O[q=mi*16+fr][d=dt*16+fg*4+r]
  float l_part[2] = {0.f, 0.f};

  const int nch = 2 * qt + 2;
  for (int c = 0; c < nch; c++) {
    const int k0 = c * 64;
    __syncthreads();  // prior chunk's Ks/Vs reads complete
    {
      const unsigned short* Kt = Krow + (size_t)k0 * HD_;
      for (int i = wave; i < 10; i += 4)
        GLOAD_LDS16(Kt + i * 512 + lane * 8, &Ks[i * 512]);
    }
    {
      const unsigned short* Vt = Vtile + (size_t)c * 5120;
      for (int i = wave; i < 10; i += 4)
        GLOAD_LDS16(Vt + i * 512 + lane * 8, &Vs[i * 512]);
    }
    __syncthreads();  // drains DMA

    // S^T = K Q^T: accST[ni][mi] lane holds P[q=mi*16+fr][k=ni*16+fg*4+r]
    floatx4 accST[4][2] = {};
#pragma unroll
    for (int ni = 0; ni < 4; ni++) {
      const unsigned short* kp = &Ks[(ni * 16 + fr) * 80];
      const short8 kf0 = *(const short8*)&kp[fg * 8];
      const short8 kf1 = *(const short8*)&kp[32 + fg * 8];
      const short8 kf2 = *(const short8*)&kp[64 + (fg & 1) * 8];  // fg>=2: qf side is zero
      accST[ni][0] = __builtin_amdgcn_mfma_f32_16x16x32_bf16(kf0, qf[0][0], accST[ni][0], 0, 0, 0);
      accST[ni][1] = __builtin_amdgcn_mfma_f32_16x16x32_bf16(kf0, qf[1][0], accST[ni][1], 0, 0, 0);
      accST[ni][0] = __builtin_amdgcn_mfma_f32_16x16x32_bf16(kf1, qf[0][1], accST[ni][0], 0, 0, 0);
      accST[ni][1] = __builtin_amdgcn_mfma_f32_16x16x32_bf16(kf1, qf[1][1], accST[ni][1], 0, 0, 0);
      accST[ni][0] = __builtin_amdgcn_mfma_f32_16x16x32_bf16(kf2, qf[0][2], accST[ni][0], 0, 0, 0);
      accST[ni][1] = __builtin_amdgcn_mfma_f32_16x16x32_bf16(kf2, qf[1][2], accST[ni][1], 0, 0, 0);
    }

    // causal mask (diagonal-crossing chunks only)
    if (k0 + 63 > qbase) {
#pragma unroll
      for (int ni = 0; ni < 4; ni++)
#pragma unroll
        for (int mi = 0; mi < 2; mi++) {
          const int qg = qbase + mi * 16 + fr;
#pragma unroll
          for (int r = 0; r < 4; r++) {
            const int kg = k0 + ni * 16 + fg * 4 + r;
            if (kg > qg) accST[ni][mi][r] = -1e30f;
          }
        }
    }

    // per 32-key half: exp2 -> packed P^T to LDS -> PV MFMA
#pragma unroll
    for (int hh = 0; hh < 2; hh++) {
#pragma unroll
      for (int nh = 0; nh < 2; nh++) {
        const int ni = hh * 2 + nh;
#pragma unroll
        for (int mi = 0; mi < 2; mi++) {
          const float p0 = __builtin_amdgcn_exp2f(accST[ni][mi][0]);
          const float p1 = __builtin_amdgcn_exp2f(accST[ni][mi][1]);
          const float p2 = __builtin_amdgcn_exp2f(accST[ni][mi][2]);
          const float p3 = __builtin_amdgcn_exp2f(accST[ni][mi][3]);
          l_part[mi] += (p0 + p1) + (p2 + p3);
          uint2 w;
          w.x = (unsigned)f2bf(p0) | ((unsigned)f2bf(p1) << 16);
          w.y = (unsigned)f2bf(p2) | ((unsigned)f2bf(p3) << 16);
          *(uint2*)&Ts[wave][(mi * 16 + fr) * 40 + nh * 16 + fg * 4] = w;
        }
      }
      // wave-local write->read; compiler inserts lgkmcnt
      const short8 pf0 = *(const short8*)&Ts[wave][fr * 40 + fg * 8];
      const short8 pf1 = *(const short8*)&Ts[wave][(16 + fr) * 40 + fg * 8];
      const int vcol = hh * 32 + fg * 8;
#pragma unroll
      for (int dt = 0; dt < 5; dt++) {
        const short8 vf = *(const short8*)&Vs[(dt * 16 + fr) * 64 + (vcol ^ ((fr & 7) * 8))];
        accOT[dt][0] = __builtin_amdgcn_mfma_f32_16x16x32_bf16(vf, pf0, accOT[dt][0], 0, 0, 0);
        accOT[dt][1] = __builtin_amdgcn_mfma_f32_16x16x32_bf16(vf, pf1, accOT[dt][1], 0, 0, 0);
      }
    }
  }

  // epilogue: l reduce across fg lanes; packed b64 ctx stores (4 consecutive d)
  const int b = bh >> 5, h2 = bh & 31;
#pragma unroll
  for (int mi = 0; mi < 2; mi++) {
    float s = l_part[mi];
    s += __shfl_xor(s, 16);
    s += __shfl_xor(s, 32);
    const float inv = 1.f / s;
    const size_t rowoff = (size_t)(b * S_ + qbase + mi * 16 + fr) * D_ + h2 * HD_;
#pragma unroll
    for (int dt = 0; dt < 5; dt++) {
      const float v0 = accOT[dt][mi][0] * inv;
      const float v1 = accOT[dt][mi][1] * inv;
      const float v2 = accOT[dt][mi][2] * inv;
      const float v3 = accOT[dt][mi][3] * inv;
      uint2 w;
      w.x = (unsigned)f2bf(v0) | ((unsigned)f2bf(v1) << 16);
      w.y = (unsigned)f2bf(v2) | ((unsigned)f2bf(v3) << 16);
      *(uint2*)&ctx[rowoff + dt * 16 + fg * 4] = w;
    }
  }
}

extern "C" void kernel_launch(void* const* d_in, const int* in_sizes, int n_in,
                              void* d_out, int out_size, void* d_ws, size_t ws_size,
                              hipStream_t stream) {
  (void)in_sizes; (void)n_in; (void)out_size; (void)ws_size;
  const float* x      = (const float*)d_in[0];
  const float* wqkv_w = (const float*)d_in[1];
  const float* wqkv_b = (const float*)d_in[2];
  const float* out_w  = (const float*)d_in[3];
  const float* out_b  = (const float*)d_in[4];
  char* ws = (char*)d_ws;

  unsigned short* Xb    = (unsigned short*)(ws + 0);          // 4096x2560 bf16
  unsigned short* Wqkvb = (unsigned short*)(ws + 20971520);   // 7680x2560 bf16 (dead after gemm1)
  unsigned short* qkv   = (unsigned short*)(ws + 60293120);   // 4096x7680 bf16
  unsigned short* Qb    = (unsigned short*)(ws + 123207680);  // [B,H,S,80] bf16
  unsigned short* Kb    = (unsigned short*)(ws + 144179200);  // [B,H,S,80] bf16
  unsigned short* Woutb = (unsigned short*)(ws + 165150720);  // 2560x2560 bf16; end 178.3 MB
  unsigned short* ctx   = Xb;                                 // Xb dead after gemm1
  unsigned short* Vtile = (unsigned short*)(ws + 34078720);   // 21.0 MB in dead Wqkvb tail

  cvt3_kernel<<<35840, 256, 0, stream>>>(x, Xb, 2621440,
                                         wqkv_w, Wqkvb, 4915200,
                                         out_w, Woutb, 1638400);
  gemm_bt<1><<<dim3(60, 32), 256, 0, stream>>>(Xb, Wqkvb, wqkv_b, (void*)qkv, 4096, 7680, 2560);
  rope_kernel<<<512, 256, 0, stream>>>(qkv, Qb, Kb);
  vtrans_kernel<<<dim3(32, 64), 256, 0, stream>>>(qkv, Vtile);
  attn_mfma<<<dim3(16, 64), 256, 0, stream>>>(Qb, Kb, Vtile, ctx);
  gemm_bt<0><<<dim3(20, 32), 256, 0, stream>>>(ctx, Woutb, out_b, d_out, 4096, 2560, 2560);
}